// Round 1
// baseline (720.115 us; speedup 1.0000x reference)
//
#include <hip/hip_runtime.h>

#define NNODES 100000
#define FH 64
#define NEG_SLOPE 0.2f

// ---------------- CSR build ----------------

__global__ void k_hist(const int* __restrict__ dst, int* __restrict__ counts, int E) {
    int i = blockIdx.x * blockDim.x + threadIdx.x;
    if (i < E) atomicAdd(&counts[dst[i]], 1);
}

// Per-256-chunk exclusive scan; block totals to bsums.
__global__ void k_scanA(const int* __restrict__ counts, int* __restrict__ offs,
                        int* __restrict__ bsums, int N) {
    __shared__ int buf[2][256];
    int t = threadIdx.x;
    int idx = blockIdx.x * 256 + t;
    int v = (idx < N) ? counts[idx] : 0;
    buf[0][t] = v;
    __syncthreads();
    int pi = 0;
    for (int d = 1; d < 256; d <<= 1) {
        int po = pi ^ 1;
        buf[po][t] = buf[pi][t] + (t >= d ? buf[pi][t - d] : 0);
        pi = po;
        __syncthreads();
    }
    if (idx < N) offs[idx] = buf[pi][t] - v;       // exclusive within block
    if (t == 255) bsums[blockIdx.x] = buf[pi][255]; // block total
}

// Exclusive scan of block sums (nb <= 512), in place.
__global__ void k_scanB(int* __restrict__ bsums, int nb) {
    __shared__ int buf[2][512];
    int t = threadIdx.x;
    int v = (t < nb) ? bsums[t] : 0;
    buf[0][t] = v;
    __syncthreads();
    int pi = 0;
    for (int d = 1; d < 512; d <<= 1) {
        int po = pi ^ 1;
        buf[po][t] = buf[pi][t] + (t >= d ? buf[pi][t - d] : 0);
        pi = po;
        __syncthreads();
    }
    if (t < nb) bsums[t] = buf[pi][t] - v;          // exclusive
}

__global__ void k_scanC(int* __restrict__ offs, const int* __restrict__ bsums, int N, int E) {
    int idx = blockIdx.x * 256 + threadIdx.x;
    if (idx < N) offs[idx] += bsums[blockIdx.x];
    if (idx == 0) offs[N] = E;
}

__global__ void k_scatter(const int* __restrict__ src, const int* __restrict__ dst,
                          const int* __restrict__ offs, int* __restrict__ cursor,
                          int* __restrict__ csr_src, int E) {
    int i = blockIdx.x * blockDim.x + threadIdx.x;
    if (i < E) {
        int d = dst[i];
        int pos = offs[d] + atomicAdd(&cursor[d], 1);
        csr_src[pos] = src[i];
    }
}

// ---------------- fused GEMM + attention projections ----------------
// One wave per row: lane = output feature. W staged in LDS.
// h[row, lane] = dot(x[row,:], W[:,lane]); el/er = wave-reduced dot(h, al/ar).

template <int FIN>
__global__ __launch_bounds__(256) void k_gemm(const float* __restrict__ x,
                                              const float* __restrict__ W,
                                              const float* __restrict__ al,
                                              const float* __restrict__ ar,
                                              float* __restrict__ h,
                                              float* __restrict__ el,
                                              float* __restrict__ er, int N) {
    __shared__ float Wl[FIN * 64];
    for (int i = threadIdx.x; i < FIN * 16; i += 256)
        ((float4*)Wl)[i] = ((const float4*)W)[i];
    __syncthreads();

    int wave = threadIdx.x >> 6, lane = threadIdx.x & 63;
    int row = blockIdx.x * 4 + wave;
    if (row >= N) return;

    const float4* xr = (const float4*)(x + (size_t)row * FIN);
    float acc = 0.f;
#pragma unroll
    for (int k4 = 0; k4 < FIN / 4; ++k4) {
        float4 xv = xr[k4];
        acc = fmaf(xv.x, Wl[(4 * k4 + 0) * 64 + lane], acc);
        acc = fmaf(xv.y, Wl[(4 * k4 + 1) * 64 + lane], acc);
        acc = fmaf(xv.z, Wl[(4 * k4 + 2) * 64 + lane], acc);
        acc = fmaf(xv.w, Wl[(4 * k4 + 3) * 64 + lane], acc);
    }
    h[(size_t)row * 64 + lane] = acc;

    float e1 = acc * al[lane];
    float e2 = acc * ar[lane];
#pragma unroll
    for (int o = 32; o; o >>= 1) {
        e1 += __shfl_xor(e1, o);
        e2 += __shfl_xor(e2, o);
    }
    if (lane == 0) {
        el[row] = e1;
        er[row] = e2;
    }
}

// ---------------- edge softmax + aggregation ----------------
// One wave per dst node. Pass1: max (lane-parallel over edges).
// Pass2: denom. Pass3: serial edge loop, lane = feature, register accumulate.

__global__ __launch_bounds__(256) void k_agg(const float* __restrict__ h,
                                             const float* __restrict__ el,
                                             const float* __restrict__ er,
                                             const float* __restrict__ b,
                                             const int* __restrict__ offs,
                                             const int* __restrict__ csr_src,
                                             float* __restrict__ out, int N, int relu) {
    int wave = threadIdx.x >> 6, lane = threadIdx.x & 63;
    int n = blockIdx.x * 4 + wave;
    if (n >= N) return;

    int beg = offs[n], end = offs[n + 1];
    float ern = er[n];

    float m = -1e30f;
    for (int i = beg + lane; i < end; i += 64) {
        float e = el[csr_src[i]] + ern;
        e = e > 0.f ? e : NEG_SLOPE * e;
        m = fmaxf(m, e);
    }
#pragma unroll
    for (int o = 32; o; o >>= 1) m = fmaxf(m, __shfl_xor(m, o));

    float s = 0.f;
    for (int i = beg + lane; i < end; i += 64) {
        float e = el[csr_src[i]] + ern;
        e = e > 0.f ? e : NEG_SLOPE * e;
        s += __expf(e - m);
    }
#pragma unroll
    for (int o = 32; o; o >>= 1) s += __shfl_xor(s, o);
    float inv = 1.f / fmaxf(s, 1e-9f);

    float acc = 0.f;
    for (int i = beg; i < end; ++i) {
        int sidx = csr_src[i];                  // wave-uniform broadcast load
        float e = el[sidx] + ern;
        e = e > 0.f ? e : NEG_SLOPE * e;
        float a = __expf(e - m) * inv;
        acc = fmaf(a, h[(size_t)sidx * 64 + lane], acc);  // coalesced 256B
    }
    float o = acc + b[lane];
    if (relu) o = fmaxf(o, 0.f);
    out[(size_t)n * 64 + lane] = o;
}

// ---------------- launch ----------------

extern "C" void kernel_launch(void* const* d_in, const int* in_sizes, int n_in,
                              void* d_out, int out_size, void* d_ws, size_t ws_size,
                              hipStream_t stream) {
    const float* x   = (const float*)d_in[0];
    const int*   src = (const int*)d_in[1];
    const int*   dst = (const int*)d_in[2];
    const float* W1  = (const float*)d_in[3];
    const float* al1 = (const float*)d_in[4];
    const float* ar1 = (const float*)d_in[5];
    const float* b1  = (const float*)d_in[6];
    const float* W2  = (const float*)d_in[7];
    const float* al2 = (const float*)d_in[8];
    const float* ar2 = (const float*)d_in[9];
    const float* b2  = (const float*)d_in[10];
    float* out = (float*)d_out;

    const int N = NNODES;
    const int E = in_sizes[1];

    // workspace layout (all 4-byte elements)
    float* h    = (float*)d_ws;              // N*64
    float* hmid = h + (size_t)N * 64;        // N*64
    float* el   = hmid + (size_t)N * 64;     // N
    float* er   = el + N;                    // N
    int* counts = (int*)(er + N);            // N
    int* cursor = counts + N;                // N
    int* offs   = cursor + N;                // N+1
    int* csrs   = offs + N + 1;              // E
    int* bsums  = csrs + E;                  // <=512

    int nbN = (N + 255) / 256;  // 391 (<=512 for scanB)
    int nbE = (E + 255) / 256;

    hipMemsetAsync(counts, 0, (size_t)N * sizeof(int), stream);
    hipMemsetAsync(cursor, 0, (size_t)N * sizeof(int), stream);

    k_hist<<<nbE, 256, 0, stream>>>(dst, counts, E);
    k_scanA<<<nbN, 256, 0, stream>>>(counts, offs, bsums, N);
    k_scanB<<<1, 512, 0, stream>>>(bsums, nbN);
    k_scanC<<<nbN, 256, 0, stream>>>(offs, bsums, N, E);
    k_scatter<<<nbE, 256, 0, stream>>>(src, dst, offs, cursor, csrs, E);

    int nbR = (N + 3) / 4;
    // layer 1
    k_gemm<128><<<nbR, 256, 0, stream>>>(x, W1, al1, ar1, h, el, er, N);
    k_agg<<<nbR, 256, 0, stream>>>(h, el, er, b1, offs, csrs, hmid, N, 1);
    // layer 2
    k_gemm<64><<<nbR, 256, 0, stream>>>(hmid, W2, al2, ar2, h, el, er, N);
    k_agg<<<nbR, 256, 0, stream>>>(h, el, er, b2, offs, csrs, out, N, 0);
}